// Round 1
// baseline (235.923 us; speedup 1.0000x reference)
//
#include <hip/hip_runtime.h>
#include <math.h>

#define HDIM 4096
#define THREADS 256
#define CHUNK 4          // HDIM / (THREADS * 4) float4 chunks per thread
#define EPSV 1e-6f

__device__ __forceinline__ float waveSum(float v) {
    #pragma unroll
    for (int o = 32; o > 0; o >>= 1) v += __shfl_xor(v, o);
    return v;
}
__device__ __forceinline__ float waveMax(float v) {
    #pragma unroll
    for (int o = 32; o > 0; o >>= 1) v = fmaxf(v, __shfl_xor(v, o));
    return v;
}

// One block per row of 4096. Fused: x = x1+x2; rmsnorm; smooth-quant; plain-quant.
// Writes all 10 reference outputs (7 full tensors + 3 scale vectors), f32.
__global__ __launch_bounds__(THREADS) void fused_add_rmsnorm_quant(
    const float* __restrict__ x1, const float* __restrict__ x2,
    const float* __restrict__ w,  const float* __restrict__ sm,
    float* __restrict__ out, const long long N, const long long R)
{
    __shared__ float redA[4];
    __shared__ float redB[4];

    const long long row  = blockIdx.x;
    const int tid  = threadIdx.x;
    const int wave = tid >> 6;
    const int lane = tid & 63;
    const long long base = row * (long long)HDIM;

    float xv[CHUNK][4];   // x1+x2
    float yv[CHUNK][4];   // normalized
    float sv[CHUNK][4];   // smoothed

    // ---- pass 1: load, add, sum of squares (all kept in registers) ----
    float ss = 0.f;
    #pragma unroll
    for (int c = 0; c < CHUNK; ++c) {
        const long long idx = base + (long long)(c * (THREADS * 4) + tid * 4);
        const float4 a = *reinterpret_cast<const float4*>(x1 + idx);
        const float4 b = *reinterpret_cast<const float4*>(x2 + idx);
        xv[c][0] = a.x + b.x;
        xv[c][1] = a.y + b.y;
        xv[c][2] = a.z + b.z;
        xv[c][3] = a.w + b.w;
        #pragma unroll
        for (int j = 0; j < 4; ++j) ss += xv[c][j] * xv[c][j];
    }
    ss = waveSum(ss);
    if (lane == 0) redA[wave] = ss;
    __syncthreads();
    ss = (redA[0] + redA[1]) + (redA[2] + redA[3]);
    const float inv = 1.0f / sqrtf(ss * (1.0f / HDIM) + EPSV);
    __syncthreads();   // redA reused below

    // ---- pass 2: normalize, smooth, track both row maxima ----
    float mS = 0.f, mY = 0.f;
    #pragma unroll
    for (int c = 0; c < CHUNK; ++c) {
        const int col = c * (THREADS * 4) + tid * 4;
        const float4 wv  = *reinterpret_cast<const float4*>(w  + col);
        const float4 smv = *reinterpret_cast<const float4*>(sm + col);
        const float wa[4] = { wv.x,  wv.y,  wv.z,  wv.w  };
        const float sa[4] = { smv.x, smv.y, smv.z, smv.w };
        #pragma unroll
        for (int j = 0; j < 4; ++j) {
            const float y = xv[c][j] * inv * wa[j];
            const float s = y * sa[j];
            yv[c][j] = y;
            sv[c][j] = s;
            mY = fmaxf(mY, fabsf(y));
            mS = fmaxf(mS, fabsf(s));
        }
    }
    mS = waveMax(mS);
    mY = waveMax(mY);
    if (lane == 0) { redA[wave] = mS; redB[wave] = mY; }
    __syncthreads();
    mS = fmaxf(fmaxf(redA[0], redA[1]), fmaxf(redA[2], redA[3]));
    mY = fmaxf(fmaxf(redB[0], redB[1]), fmaxf(redB[2], redB[3]));

    const float scale1 = mS * (1.0f / 127.0f);
    const float scale3 = mY * (1.0f / 127.0f);
    const float rs1 = 1.0f / scale1;
    const float rs3 = 1.0f / scale3;

    // ---- output layout: 10 outputs concatenated flat, all f32 ----
    float* out_q   = out;                 // yOut        [N] int8-as-float
    float* out_x   = out + N;             // xOut        [N]
    float* out_s1  = out + 2 * N;         // scale1Out   [R]
    float* out_y   = out + 2 * N + R;     // y1_flat     [N]
    float* out_xb  = out + 3 * N + R;     // xOut1       [N]
    float* out_q2  = out + 4 * N + R;     // yOut2       [N]
    float* out_s2  = out + 5 * N + R;     // scale1Out2  [R]
    float* out_x3  = out + 5 * N + 2 * R; // xOut3       [N]
    float* out_q3  = out + 6 * N + 2 * R; // yOut3       [N]
    float* out_s3  = out + 7 * N + 2 * R; // scale1Out3  [R]

    // ---- pass 3: quantize + write everything (float4 stores) ----
    #pragma unroll
    for (int c = 0; c < CHUNK; ++c) {
        const long long idx = base + (long long)(c * (THREADS * 4) + tid * 4);
        const float4 xq = make_float4(xv[c][0], xv[c][1], xv[c][2], xv[c][3]);
        const float4 yq = make_float4(yv[c][0], yv[c][1], yv[c][2], yv[c][3]);
        const float4 qf = make_float4(rintf(sv[c][0] * rs1), rintf(sv[c][1] * rs1),
                                      rintf(sv[c][2] * rs1), rintf(sv[c][3] * rs1));
        const float4 q3 = make_float4(rintf(yv[c][0] * rs3), rintf(yv[c][1] * rs3),
                                      rintf(yv[c][2] * rs3), rintf(yv[c][3] * rs3));
        *reinterpret_cast<float4*>(out_q  + idx) = qf;
        *reinterpret_cast<float4*>(out_x  + idx) = xq;
        *reinterpret_cast<float4*>(out_y  + idx) = yq;
        *reinterpret_cast<float4*>(out_xb + idx) = xq;
        *reinterpret_cast<float4*>(out_q2 + idx) = qf;
        *reinterpret_cast<float4*>(out_x3 + idx) = xq;
        *reinterpret_cast<float4*>(out_q3 + idx) = q3;
    }
    if (tid == 0) {
        out_s1[row] = scale1;
        out_s2[row] = scale1;
        out_s3[row] = scale3;
    }
}

extern "C" void kernel_launch(void* const* d_in, const int* in_sizes, int n_in,
                              void* d_out, int out_size, void* d_ws, size_t ws_size,
                              hipStream_t stream) {
    const float* x1 = (const float*)d_in[0];
    const float* x2 = (const float*)d_in[1];
    const float* w  = (const float*)d_in[2];
    const float* sm = (const float*)d_in[3];
    float* out = (float*)d_out;

    const long long N = (long long)in_sizes[0];   // 2*4096*4096
    const long long R = N / HDIM;                 // 8192 rows

    fused_add_rmsnorm_quant<<<dim3((unsigned)R), dim3(THREADS), 0, stream>>>(
        x1, x2, w, sm, out, N, R);
}

// Round 3
// 232.303 us; speedup vs baseline: 1.0156x; 1.0156x over previous
//
#include <hip/hip_runtime.h>
#include <math.h>

#define HDIM 4096
#define THREADS 256
#define CHUNK 4          // HDIM / (THREADS * 4) float4 chunks per thread
#define EPSV 1e-6f

typedef float f4 __attribute__((ext_vector_type(4)));   // native vec for NT builtins

__device__ __forceinline__ float waveSum(float v) {
    #pragma unroll
    for (int o = 32; o > 0; o >>= 1) v += __shfl_xor(v, o);
    return v;
}
__device__ __forceinline__ float waveMax(float v) {
    #pragma unroll
    for (int o = 32; o > 0; o >>= 1) v = fmaxf(v, __shfl_xor(v, o));
    return v;
}

// One block per row of 4096. Single-load fused kernel:
//   pass 1: x = x1+x2 (kept in regs); accumulate ss = sum(x^2),
//           mW = max|x*w|, mSm = max|x*w*sm|   (inv factors out of the maxima)
//   reduce once; pass 2: recompute y/s from xv + re-read w,sm (L1-hot), write
//   all 7 full output streams + 3 scale vectors with nontemporal stores.
__global__ __launch_bounds__(THREADS) void fused_add_rmsnorm_quant(
    const float* __restrict__ x1, const float* __restrict__ x2,
    const float* __restrict__ w,  const float* __restrict__ sm,
    float* __restrict__ out, const long long N, const long long R)
{
    __shared__ float redS[4];
    __shared__ float redW[4];
    __shared__ float redM[4];

    const long long row  = blockIdx.x;
    const int tid  = threadIdx.x;
    const int wave = tid >> 6;
    const int lane = tid & 63;
    const long long base = row * (long long)HDIM;

    f4 xv[CHUNK];   // x1+x2 — the only state held across the barrier

    // ---- pass 1: load, add, all three row statistics ----
    float ss = 0.f, mW = 0.f, mSm = 0.f;
    #pragma unroll
    for (int c = 0; c < CHUNK; ++c) {
        const int col = c * (THREADS * 4) + tid * 4;
        const long long idx = base + col;
        const f4 a = __builtin_nontemporal_load(
            reinterpret_cast<const f4*>(x1 + idx));
        const f4 b = __builtin_nontemporal_load(
            reinterpret_cast<const f4*>(x2 + idx));
        const f4 wv  = *reinterpret_cast<const f4*>(w  + col);
        const f4 smv = *reinterpret_cast<const f4*>(sm + col);
        const f4 x = a + b;
        xv[c] = x;
        #pragma unroll
        for (int j = 0; j < 4; ++j) {
            const float t = x[j] * wv[j];     // x*w  (y = t*inv)
            ss += x[j] * x[j];
            mW  = fmaxf(mW,  fabsf(t));
            mSm = fmaxf(mSm, fabsf(t * smv[j]));
        }
    }
    ss  = waveSum(ss);
    mW  = waveMax(mW);
    mSm = waveMax(mSm);
    if (lane == 0) { redS[wave] = ss; redW[wave] = mW; redM[wave] = mSm; }
    __syncthreads();
    ss  = (redS[0] + redS[1]) + (redS[2] + redS[3]);
    mW  = fmaxf(fmaxf(redW[0], redW[1]), fmaxf(redW[2], redW[3]));
    mSm = fmaxf(fmaxf(redM[0], redM[1]), fmaxf(redM[2], redM[3]));

    const float inv    = 1.0f / sqrtf(ss * (1.0f / HDIM) + EPSV);
    const float scale1 = (inv * mSm) * (1.0f / 127.0f);
    const float scale3 = (inv * mW)  * (1.0f / 127.0f);
    const float rs1 = 1.0f / scale1;
    const float rs3 = 1.0f / scale3;

    // ---- output layout: 10 outputs concatenated flat, all f32 ----
    float* out_q   = out;                 // yOut        [N]
    float* out_x   = out + N;             // xOut        [N]
    float* out_s1  = out + 2 * N;         // scale1Out   [R]
    float* out_y   = out + 2 * N + R;     // y1_flat     [N]
    float* out_xb  = out + 3 * N + R;     // xOut1       [N]
    float* out_q2  = out + 4 * N + R;     // yOut2       [N]
    float* out_s2  = out + 5 * N + R;     // scale1Out2  [R]
    float* out_x3  = out + 5 * N + 2 * R; // xOut3       [N]
    float* out_q3  = out + 6 * N + 2 * R; // yOut3       [N]
    float* out_s3  = out + 7 * N + 2 * R; // scale1Out3  [R]

    // ---- pass 2: recompute y/s from registers, quantize, stream out ----
    #pragma unroll
    for (int c = 0; c < CHUNK; ++c) {
        const int col = c * (THREADS * 4) + tid * 4;
        const long long idx = base + col;
        const f4 wv  = *reinterpret_cast<const f4*>(w  + col);
        const f4 smv = *reinterpret_cast<const f4*>(sm + col);
        f4 xq, yq, qf, q3;
        #pragma unroll
        for (int j = 0; j < 4; ++j) {
            const float x = xv[c][j];
            const float y = x * inv * wv[j];
            const float s = y * smv[j];
            xq[j] = x;
            yq[j] = y;
            qf[j] = rintf(s * rs1);
            q3[j] = rintf(y * rs3);
        }
        __builtin_nontemporal_store(qf, reinterpret_cast<f4*>(out_q  + idx));
        __builtin_nontemporal_store(xq, reinterpret_cast<f4*>(out_x  + idx));
        __builtin_nontemporal_store(yq, reinterpret_cast<f4*>(out_y  + idx));
        __builtin_nontemporal_store(xq, reinterpret_cast<f4*>(out_xb + idx));
        __builtin_nontemporal_store(qf, reinterpret_cast<f4*>(out_q2 + idx));
        __builtin_nontemporal_store(xq, reinterpret_cast<f4*>(out_x3 + idx));
        __builtin_nontemporal_store(q3, reinterpret_cast<f4*>(out_q3 + idx));
    }
    if (tid == 0) {
        out_s1[row] = scale1;
        out_s2[row] = scale1;
        out_s3[row] = scale3;
    }
}

extern "C" void kernel_launch(void* const* d_in, const int* in_sizes, int n_in,
                              void* d_out, int out_size, void* d_ws, size_t ws_size,
                              hipStream_t stream) {
    const float* x1 = (const float*)d_in[0];
    const float* x2 = (const float*)d_in[1];
    const float* w  = (const float*)d_in[2];
    const float* sm = (const float*)d_in[3];
    float* out = (float*)d_out;

    const long long N = (long long)in_sizes[0];   // 2*4096*4096
    const long long R = N / HDIM;                 // 8192 rows

    fused_add_rmsnorm_quant<<<dim3((unsigned)R), dim3(THREADS), 0, stream>>>(
        x1, x2, w, sm, out, N, R);
}

// Round 4
// 231.278 us; speedup vs baseline: 1.0201x; 1.0044x over previous
//
#include <hip/hip_runtime.h>
#include <math.h>

#define HDIM 4096
#define THREADS 256
#define CHUNK 4          // HDIM / (THREADS * 4) float4 chunks per thread
#define EPSV 1e-6f

typedef float f4 __attribute__((ext_vector_type(4)));   // native vec for NT builtins

__device__ __forceinline__ float waveSum(float v) {
    #pragma unroll
    for (int o = 32; o > 0; o >>= 1) v += __shfl_xor(v, o);
    return v;
}
__device__ __forceinline__ float waveMax(float v) {
    #pragma unroll
    for (int o = 32; o > 0; o >>= 1) v = fmaxf(v, __shfl_xor(v, o));
    return v;
}

// One block per row of 4096.
//   pass 1: x = x1+x2; immediately stream x to its 3 output copies (these
//           don't depend on the row statistics -> overlap writes with loads
//           and with the reduction barrier); accumulate ss, max|x*w|,
//           max|x*w*sm| (inv factors out of the maxima).
//   reduce; pass 2: y/quant from registers, write remaining 4 streams.
__global__ __launch_bounds__(THREADS) void fused_add_rmsnorm_quant(
    const float* __restrict__ x1, const float* __restrict__ x2,
    const float* __restrict__ w,  const float* __restrict__ sm,
    float* __restrict__ out, const long long N, const long long R)
{
    __shared__ float redS[4];
    __shared__ float redW[4];
    __shared__ float redM[4];

    const long long row  = blockIdx.x;
    const int tid  = threadIdx.x;
    const int wave = tid >> 6;
    const int lane = tid & 63;
    const long long base = row * (long long)HDIM;

    // ---- output layout: 10 outputs concatenated flat, all f32 ----
    float* out_q   = out;                 // yOut        [N]
    float* out_x   = out + N;             // xOut        [N]
    float* out_s1  = out + 2 * N;         // scale1Out   [R]
    float* out_y   = out + 2 * N + R;     // y1_flat     [N]
    float* out_xb  = out + 3 * N + R;     // xOut1       [N]
    float* out_q2  = out + 4 * N + R;     // yOut2       [N]
    float* out_s2  = out + 5 * N + R;     // scale1Out2  [R]
    float* out_x3  = out + 5 * N + 2 * R; // xOut3       [N]
    float* out_q3  = out + 6 * N + 2 * R; // yOut3       [N]
    float* out_s3  = out + 7 * N + 2 * R; // scale1Out3  [R]

    f4 xv[CHUNK];   // x1+x2 — the only state held across the barrier

    // ---- pass 1: load, add, write x-streams now, accumulate stats ----
    float ss = 0.f, mW = 0.f, mSm = 0.f;
    #pragma unroll
    for (int c = 0; c < CHUNK; ++c) {
        const int col = c * (THREADS * 4) + tid * 4;
        const long long idx = base + col;
        const f4 a = __builtin_nontemporal_load(
            reinterpret_cast<const f4*>(x1 + idx));
        const f4 b = __builtin_nontemporal_load(
            reinterpret_cast<const f4*>(x2 + idx));
        const f4 wv  = *reinterpret_cast<const f4*>(w  + col);
        const f4 smv = *reinterpret_cast<const f4*>(sm + col);
        const f4 x = a + b;
        xv[c] = x;
        // x-only outputs: stream out immediately (fire-and-forget)
        __builtin_nontemporal_store(x, reinterpret_cast<f4*>(out_x  + idx));
        __builtin_nontemporal_store(x, reinterpret_cast<f4*>(out_xb + idx));
        __builtin_nontemporal_store(x, reinterpret_cast<f4*>(out_x3 + idx));
        #pragma unroll
        for (int j = 0; j < 4; ++j) {
            const float t = x[j] * wv[j];     // x*w  (y = t*inv)
            ss += x[j] * x[j];
            mW  = fmaxf(mW,  fabsf(t));
            mSm = fmaxf(mSm, fabsf(t * smv[j]));
        }
    }
    ss  = waveSum(ss);
    mW  = waveMax(mW);
    mSm = waveMax(mSm);
    if (lane == 0) { redS[wave] = ss; redW[wave] = mW; redM[wave] = mSm; }
    __syncthreads();
    ss  = (redS[0] + redS[1]) + (redS[2] + redS[3]);
    mW  = fmaxf(fmaxf(redW[0], redW[1]), fmaxf(redW[2], redW[3]));
    mSm = fmaxf(fmaxf(redM[0], redM[1]), fmaxf(redM[2], redM[3]));

    const float inv    = 1.0f / sqrtf(ss * (1.0f / HDIM) + EPSV);
    const float scale1 = (inv * mSm) * (1.0f / 127.0f);
    const float scale3 = (inv * mW)  * (1.0f / 127.0f);
    const float rs1 = 1.0f / scale1;
    const float rs3 = 1.0f / scale3;

    // ---- pass 2: y + both quants from registers, write 4 streams ----
    #pragma unroll
    for (int c = 0; c < CHUNK; ++c) {
        const int col = c * (THREADS * 4) + tid * 4;
        const long long idx = base + col;
        const f4 wv  = *reinterpret_cast<const f4*>(w  + col);
        const f4 smv = *reinterpret_cast<const f4*>(sm + col);
        f4 yq, qf, q3;
        #pragma unroll
        for (int j = 0; j < 4; ++j) {
            const float x = xv[c][j];
            const float y = x * inv * wv[j];
            const float s = y * smv[j];
            yq[j] = y;
            qf[j] = rintf(s * rs1);
            q3[j] = rintf(y * rs3);
        }
        __builtin_nontemporal_store(qf, reinterpret_cast<f4*>(out_q  + idx));
        __builtin_nontemporal_store(yq, reinterpret_cast<f4*>(out_y  + idx));
        __builtin_nontemporal_store(qf, reinterpret_cast<f4*>(out_q2 + idx));
        __builtin_nontemporal_store(q3, reinterpret_cast<f4*>(out_q3 + idx));
    }
    if (tid == 0) {
        out_s1[row] = scale1;
        out_s2[row] = scale1;
        out_s3[row] = scale3;
    }
}

extern "C" void kernel_launch(void* const* d_in, const int* in_sizes, int n_in,
                              void* d_out, int out_size, void* d_ws, size_t ws_size,
                              hipStream_t stream) {
    const float* x1 = (const float*)d_in[0];
    const float* x2 = (const float*)d_in[1];
    const float* w  = (const float*)d_in[2];
    const float* sm = (const float*)d_in[3];
    float* out = (float*)d_out;

    const long long N = (long long)in_sizes[0];   // 2*4096*4096
    const long long R = N / HDIM;                 // 8192 rows

    fused_add_rmsnorm_quant<<<dim3((unsigned)R), dim3(THREADS), 0, stream>>>(
        x1, x2, w, sm, out, N, R);
}